// Round 4
// baseline (405.086 us; speedup 1.0000x reference)
//
#include <hip/hip_runtime.h>
#include <stdint.h>

#define B_SZ   32768
#define F_SZ   512
#define G_SZ   16
#define L_SZ   64
#define N_COLS 1024   // G*L
#define C_SZ   1000
#define M_TILE 64
#define A_STRIDE 520     // ushorts per LDS A row (512+8; keeps 16B alignment)
#define OUT_STRIDE 1024  // floats per outLDS row (cls < 1000; cols 1000..1023 stay zero)
// smem union: A-stage 64*520*2 = 66560 B  vs  outLDS 16*1024*4 = 65536 B
#define SMEM_WORDS 16640 // 66560 / 4

typedef __attribute__((ext_vector_type(8))) short short8;
typedef __attribute__((ext_vector_type(4))) float floatx4;

__device__ __forceinline__ unsigned short f2bf(float f) {
    unsigned int x = __float_as_uint(f);
    x += 0x7fffu + ((x >> 16) & 1u);   // RNE to bf16
    return (unsigned short)(x >> 16);
}

// Raw workgroup barrier WITHOUT the vmcnt(0) drain __syncthreads() implies.
// Every sync point in mhc_main is an LDS-only hazard (ds_write/ds_add/ds_read
// visibility -> lgkmcnt). Global out-stores are never read back; global loads
// are consumed via registers (compiler inserts vmcnt at use). Measured r3:
// this barrier form alone was 133 -> 120 us vs __syncthreads.
__device__ __forceinline__ void barrier_lgkm() {
    __builtin_amdgcn_sched_barrier(0);
    asm volatile("s_waitcnt lgkmcnt(0)" ::: "memory");
    __builtin_amdgcn_s_barrier();
    __builtin_amdgcn_sched_barrier(0);
}

// ---- kernel 1: W f32 -> bf16, natural order (no permutation needed anymore) ----
__global__ __launch_bounds__(256) void convert_w_kernel(const float* __restrict__ W,
                                                        unsigned short* __restrict__ Wb) {
    int idx = blockIdx.x * 256 + threadIdx.x;        // float4 index, 131072 total
    const float4* W4 = (const float4*)W;
    float4 v = W4[idx];
    ushort4 u = make_ushort4(f2bf(v.x), f2bf(v.y), f2bf(v.z), f2bf(v.w));
    ((ushort4*)Wb)[idx] = u;
}

// ---- kernel 2: fused GEMM (bf16 MFMA) + weighting + LDS-atomic class scatter ----
// Block: 1024 threads = 16 waves. Tile: 64 rows x all 1024 cols. K=512.
// r3 structure for stage/K-loop; epilogue rebuilt: instead of the CSR gather
// (divergent per-class run loop: wave pays max-run ~4-5x avg, 16 LDS reads per
// iter, behind a WL write+re-read round trip), each thread scatters its 16
// weighted acc values per pass straight into outLDS[row][class] with ds_add_f32.
// Duplicate classes accumulate correctly via HW atomic lane serialization.
// Copy-out is then a uniform stride-1 read (+re-zero) + coalesced store.
__global__ __launch_bounds__(1024, 4) void mhc_main_kernel(
        const float* __restrict__ feat,            // [B][512] f32
        const float* __restrict__ gp,              // [B][16]  f32
        const unsigned short* __restrict__ Wb,     // [1024][512] bf16
        const float* __restrict__ bias,            // [1024] f32
        const int* __restrict__ labels,            // [1024] int (class of each col)
        float* __restrict__ out)                   // [B][1000] f32
{
    __shared__ __align__(16) float smem[SMEM_WORDS]; // A-stage aliased with outLDS
    __shared__ float gp_s[M_TILE * G_SZ];            // 64 rows x 16 groups
    __shared__ float bias_s[N_COLS];
    __shared__ unsigned short cls_s[N_COLS];

    unsigned short* As = (unsigned short*)smem;
    float* OL = smem;                                // outLDS[16][OUT_STRIDE]

    const int t    = threadIdx.x;
    const int wave = t >> 6;          // 0..15  == group of this wave's cols
    const int lane = t & 63;
    const int m16  = lane & 15;
    const int quad = lane >> 4;       // 0..3
    const int r0   = blockIdx.x * M_TILE;

    // stage group_probs tile + bias + class ids (natural col order: group = col>>6)
    gp_s[t]   = gp[r0 * G_SZ + t];
    bias_s[t] = bias[t];
    cls_s[t]  = (unsigned short)labels[t];

    // stage A: 64 rows x 512 f32 -> bf16 LDS, coalesced float4 reads
    {
        const float4* f4 = (const float4*)(feat + (size_t)r0 * F_SZ);
        #pragma unroll
        for (int i = 0; i < 8; ++i) {
            int idx = t + i * 1024;            // row = idx/128, c4 = idx%128
            int row = idx >> 7;
            int c4  = idx & 127;
            float4 v = f4[idx];
            ushort4 u = make_ushort4(f2bf(v.x), f2bf(v.y), f2bf(v.z), f2bf(v.w));
            *(ushort4*)(As + row * A_STRIDE + c4 * 4) = u;
        }
    }
    barrier_lgkm();   // A + gp/bias/cls visible

    const floatx4 zero = {0.f, 0.f, 0.f, 0.f};
    floatx4 acc[4][4];
    #pragma unroll
    for (int i = 0; i < 4; ++i)
        #pragma unroll
        for (int j = 0; j < 4; ++j) acc[i][j] = zero;

    const unsigned short* aBase = As + m16 * A_STRIDE + quad * 8;
    const unsigned short* bBase = Wb + (size_t)(wave * 64 + m16) * F_SZ + quad * 8;

    #pragma unroll 4
    for (int kt = 0; kt < 16; ++kt) {             // K step = 32
        short8 a[4];
        #pragma unroll
        for (int rt = 0; rt < 4; ++rt)
            a[rt] = *(const short8*)(aBase + rt * 16 * A_STRIDE + kt * 32);
        #pragma unroll
        for (int ct = 0; ct < 4; ++ct) {
            short8 b = *(const short8*)(bBase + ct * 16 * F_SZ + kt * 32);
            #pragma unroll
            for (int rt = 0; rt < 4; ++rt)
                acc[rt][ct] = __builtin_amdgcn_mfma_f32_16x16x32_bf16(a[rt], b, acc[rt][ct], 0, 0, 0);
        }
    }

    // As is dead; zero the aliased class accumulator (16 rows x 1024 cols f32)
    barrier_lgkm();
    {
        #pragma unroll
        for (int i = 0; i < 4; ++i)
            *(floatx4*)(OL + i * 4096 + t * 4) = zero;
    }
    barrier_lgkm();

    // 4 passes of 16 rows: scatter-add weighted acc into OL[row][class], then
    // uniform copy-out (+re-zero for the next pass).
    #pragma unroll
    for (int p = 0; p < 4; ++p) {
        #pragma unroll
        for (int ct = 0; ct < 4; ++ct) {
            int col = wave * 64 + ct * 16 + m16;
            int cls = cls_s[col];
            float bi = bias_s[col];
            #pragma unroll
            for (int r = 0; r < 4; ++r) {
                int rl = quad * 4 + r;                       // local row 0..15 (C/D layout)
                float v = gp_s[(p * 16 + rl) * G_SZ + wave] * (acc[p][ct][r] + bi);
                atomicAdd(&OL[rl * OUT_STRIDE + cls], v);    // ds_add_f32
            }
        }
        barrier_lgkm();   // all atomics visible
        if (t < C_SZ) {
            #pragma unroll
            for (int h = 0; h < 16; ++h) {
                float v = OL[h * OUT_STRIDE + t];
                OL[h * OUT_STRIDE + t] = 0.f;                // re-zero for next pass
                out[(size_t)(r0 + p * 16 + h) * C_SZ + t] = v;  // fire-and-forget
            }
        }
        barrier_lgkm();   // copy-out reads + re-zero done before next pass's atomics
    }
}

extern "C" void kernel_launch(void* const* d_in, const int* in_sizes, int n_in,
                              void* d_out, int out_size, void* d_ws, size_t ws_size,
                              hipStream_t stream) {
    const float* feat  = (const float*)d_in[0];
    const float* gp    = (const float*)d_in[1];
    const float* W     = (const float*)d_in[2];
    const float* bias  = (const float*)d_in[3];
    const int* labels  = (const int*)d_in[4];
    float* out = (float*)d_out;

    unsigned short* Wb = (unsigned short*)d_ws;   // 1 MiB bf16 W

    convert_w_kernel<<<(N_COLS * F_SZ / 4) / 256, 256, 0, stream>>>(W, Wb);
    mhc_main_kernel<<<B_SZ / M_TILE, 1024, 0, stream>>>(feat, gp, Wb, bias, labels, out);
}

// Round 5
// 278.456 us; speedup vs baseline: 1.4548x; 1.4548x over previous
//
#include <hip/hip_runtime.h>
#include <stdint.h>

#define B_SZ   32768
#define F_SZ   512
#define G_SZ   16
#define L_SZ   64
#define N_COLS 1024   // G*L
#define C_SZ   1000
#define M_TILE 64
#define A_STRIDE 520    // ushorts per LDS A row (512+8; keeps 16B alignment, breaks pow2 stride)
#define WT_STRIDE 20    // floats per transposed weighted col (16 rows + 4 pad).
                        // 20 words = odd-multiple-of-4 stride: bank quartet = (5*col+quad)%8,
                        // 5 odd -> random cols spread uniformly over all 8 quartets = structural
                        // minimum bank load for b128, no swizzle needed.
#define SMEM_BYTES 81920  // max(A 64*520*2 = 66560, WT 1024*20*4 = 81920)

typedef __attribute__((ext_vector_type(8))) short short8;
typedef __attribute__((ext_vector_type(4))) float floatx4;

__device__ __forceinline__ unsigned short f2bf(float f) {
    unsigned int x = __float_as_uint(f);
    x += 0x7fffu + ((x >> 16) & 1u);   // RNE to bf16
    return (unsigned short)(x >> 16);
}

// Raw workgroup barrier WITHOUT the vmcnt(0) drain __syncthreads() implies.
// All sync points in mhc_main are LDS-only hazards -> lgkmcnt(0) suffices.
// Out-stores are never read back; global loads are reg-guarded by the compiler.
// Measured r3: this alone was 133 -> 120 us vs __syncthreads.
__device__ __forceinline__ void barrier_lgkm() {
    __builtin_amdgcn_sched_barrier(0);
    asm volatile("s_waitcnt lgkmcnt(0)" ::: "memory");
    __builtin_amdgcn_s_barrier();
    __builtin_amdgcn_sched_barrier(0);
}

// ---- kernel 1: invert label_ids into CSR; emit column permutation, permuted
//      bias, per-slot group id, AND a load-balanced class order (runs sorted by
//      length, descending) so mhc's gather waves have near-uniform trip counts ----
__global__ __launch_bounds__(1024) void build_csr_kernel(const int* __restrict__ label_ids,
                                                         const float* __restrict__ bias,
                                                         int* __restrict__ list,
                                                         float* __restrict__ bias_p,
                                                         unsigned char* __restrict__ g_perm,
                                                         int* __restrict__ srt_cls,
                                                         int* __restrict__ srt_off,
                                                         int* __restrict__ srt_len) {
    __shared__ int cnt[1024];   // counts -> inclusive scan (classes padded to 1024)
    __shared__ int cur[1024];   // scatter cursors
    __shared__ int hist2[64];   // histogram of run lengths (counting sort)
    __shared__ int start2[64];
    const int t = threadIdx.x;            // 0..1023 == column index g*64+l
    cnt[t] = 0;
    if (t < 64) hist2[t] = 0;
    __syncthreads();
    const int lbl = label_ids[t];
    atomicAdd(&cnt[lbl], 1);
    __syncthreads();
    // Hillis-Steele inclusive scan over 1024 entries
    int v = cnt[t];
    #pragma unroll
    for (int d = 1; d < 1024; d <<= 1) {
        int u = (t >= d) ? cnt[t - d] : 0;
        __syncthreads();
        v += u;
        cnt[t] = v;
        __syncthreads();
    }
    // exclusive offset / run length for class t
    int ex  = (t == 0) ? 0 : cnt[t - 1];
    int len = v - ex;
    cur[t] = ex;
    __syncthreads();
    int pos = atomicAdd(&cur[lbl], 1);
    list[pos]   = t;
    bias_p[pos] = bias[t];
    g_perm[pos] = (unsigned char)(t >> 6);
    // ---- counting sort of classes by run length, descending ----
    int lc = (len < 63) ? len : 63;
    if (t < C_SZ) atomicAdd(&hist2[lc], 1);
    __syncthreads();
    if (t == 0) {
        int run = 0;
        for (int k = 63; k >= 0; --k) { start2[k] = run; run += hist2[k]; }
    }
    __syncthreads();
    if (t < C_SZ) {
        int rk = atomicAdd(&start2[lc], 1);   // rank in descending-length order
        srt_cls[rk] = t;
        srt_off[rk] = ex;
        srt_len[rk] = len;
    }
}

// ---- kernel 2: W f32 -> bf16, rows permuted into CSR-list order ----
__global__ __launch_bounds__(256) void convert_w_kernel(const float* __restrict__ W,
                                                        const int* __restrict__ list,
                                                        unsigned short* __restrict__ Wb) {
    int idx = blockIdx.x * 256 + threadIdx.x;        // float4 index, 131072 total
    int row = idx >> 7;                              // output row j
    int c4  = idx & 127;
    int src = list[row];                             // original column
    const float4* W4 = (const float4*)W;
    float4 v = W4[src * 128 + c4];
    ushort4 u = make_ushort4(f2bf(v.x), f2bf(v.y), f2bf(v.z), f2bf(v.w));
    ((ushort4*)Wb)[idx] = u;
}

// ---- kernel 3: fused GEMM (bf16 MFMA) + weighting + balanced transposed gather ----
// r3 core (measured 120 us). Epilogue changes only:
//  (a) weighted tile stored TRANSPOSED: WT[col][16 rows], stride 20 words ->
//      1 gather iter = 4x ds_read_b128 (was 16x ds_read_b32), bank-optimal.
//  (b) thread t gathers the t-th LONGEST run (srt_*) -> wave trip count = lane
//      max ~= lane mean (was ~4x mean from Poisson max over 64 lanes).
__global__ __launch_bounds__(1024, 4) void mhc_main_kernel(
        const float* __restrict__ feat,            // [B][512] f32
        const float* __restrict__ gp,              // [B][16]  f32
        const unsigned short* __restrict__ Wb,     // [1024][512] bf16, permuted rows
        const float* __restrict__ bias_p,          // [1024] f32, permuted
        const unsigned char* __restrict__ g_perm,  // [1024] group of each permuted col
        const int* __restrict__ srt_cls,           // [1000] class, desc run length
        const int* __restrict__ srt_off,           // [1000] run start
        const int* __restrict__ srt_len,           // [1000] run length
        float* __restrict__ out)                   // [B][1000] f32
{
    __shared__ __align__(16) char smem[SMEM_BYTES]; // A-stage aliased with WT tile
    __shared__ float gp_s[M_TILE * G_SZ];           // 64 rows x 16 groups
    __shared__ float bias_s[N_COLS];
    __shared__ unsigned char g_s[N_COLS];

    unsigned short* As = (unsigned short*)smem;
    float* WT = (float*)smem;

    const int t    = threadIdx.x;
    const int wave = t >> 6;          // 0..15
    const int lane = t & 63;
    const int m16  = lane & 15;
    const int quad = lane >> 4;       // 0..3
    const int r0   = blockIdx.x * M_TILE;

    // stage group_probs tile + permuted bias + per-col group
    gp_s[t]   = gp[r0 * G_SZ + t];
    bias_s[t] = bias_p[t];
    g_s[t]    = g_perm[t];

    // this thread's balanced gather assignment (pass-invariant, registers)
    int cls = 0, e0 = 0, len = 0;
    if (t < C_SZ) { cls = srt_cls[t]; e0 = srt_off[t]; len = srt_len[t]; }

    // stage A: 64 rows x 512 f32 -> bf16 LDS, coalesced float4 reads
    {
        const float4* f4 = (const float4*)(feat + (size_t)r0 * F_SZ);
        #pragma unroll
        for (int i = 0; i < 8; ++i) {
            int idx = t + i * 1024;            // row = idx/128, c4 = idx%128
            int row = idx >> 7;
            int c4  = idx & 127;
            float4 v = f4[idx];
            ushort4 u = make_ushort4(f2bf(v.x), f2bf(v.y), f2bf(v.z), f2bf(v.w));
            *(ushort4*)(As + row * A_STRIDE + c4 * 4) = u;
        }
    }
    barrier_lgkm();   // A + gp/bias/g_s visible

    const floatx4 zero = {0.f, 0.f, 0.f, 0.f};
    floatx4 acc[4][4];
    #pragma unroll
    for (int i = 0; i < 4; ++i)
        #pragma unroll
        for (int j = 0; j < 4; ++j) acc[i][j] = zero;

    const unsigned short* aBase = As + m16 * A_STRIDE + quad * 8;
    const unsigned short* bBase = Wb + (size_t)(wave * 64 + m16) * F_SZ + quad * 8;

    #pragma unroll 4
    for (int kt = 0; kt < 16; ++kt) {             // K step = 32
        short8 a[4];
        #pragma unroll
        for (int rt = 0; rt < 4; ++rt)
            a[rt] = *(const short8*)(aBase + rt * 16 * A_STRIDE + kt * 32);
        #pragma unroll
        for (int ct = 0; ct < 4; ++ct) {
            short8 b = *(const short8*)(bBase + ct * 16 * F_SZ + kt * 32);
            #pragma unroll
            for (int rt = 0; rt < 4; ++rt)
                acc[rt][ct] = __builtin_amdgcn_mfma_f32_16x16x32_bf16(a[rt], b, acc[rt][ct], 0, 0, 0);
        }
    }

    // epilogue: 4 passes of 16 rows. Transposed weighted tile -> balanced gather.
    #pragma unroll
    for (int p = 0; p < 4; ++p) {
        barrier_lgkm();   // pass 0: K-loop A-LDS reads done; later: prior gather reads done
        #pragma unroll
        for (int ct = 0; ct < 4; ++ct) {
            int col = wave * 64 + ct * 16 + m16;
            int g   = g_s[col];
            float bi = bias_s[col];
            floatx4 w;
            #pragma unroll
            for (int r = 0; r < 4; ++r) {
                int rl = quad * 4 + r;                       // local row 0..15 (C/D layout)
                w[r] = gp_s[(p * 16 + rl) * G_SZ + g] * (acc[p][ct][r] + bi);
            }
            *(floatx4*)(WT + col * WT_STRIDE + quad * 4) = w;  // ds_write_b128
        }
        barrier_lgkm();   // WT visible to gatherers
        if (t < C_SZ) {
            floatx4 s0 = zero, s1 = zero, s2 = zero, s3 = zero;
            for (int j = e0; j < e0 + len; ++j) {            // balanced: ~wave-uniform len
                const float* cb = WT + j * WT_STRIDE;
                s0 += *(const floatx4*)(cb + 0);
                s1 += *(const floatx4*)(cb + 4);
                s2 += *(const floatx4*)(cb + 8);
                s3 += *(const floatx4*)(cb + 12);
            }
            size_t rb = (size_t)(r0 + p * 16) * C_SZ + cls;  // scattered col, L2 merges
            #pragma unroll
            for (int r = 0; r < 4; ++r) {
                out[rb + (size_t)(r +  0) * C_SZ] = s0[r];
                out[rb + (size_t)(r +  4) * C_SZ] = s1[r];
                out[rb + (size_t)(r +  8) * C_SZ] = s2[r];
                out[rb + (size_t)(r + 12) * C_SZ] = s3[r];
            }
        }
    }
}

extern "C" void kernel_launch(void* const* d_in, const int* in_sizes, int n_in,
                              void* d_out, int out_size, void* d_ws, size_t ws_size,
                              hipStream_t stream) {
    const float* feat  = (const float*)d_in[0];
    const float* gp    = (const float*)d_in[1];
    const float* W     = (const float*)d_in[2];
    const float* bias  = (const float*)d_in[3];
    const int* labels  = (const int*)d_in[4];
    float* out = (float*)d_out;

    unsigned short* Wb = (unsigned short*)d_ws;                    // 1 MiB bf16 W (permuted)
    char* base = (char*)d_ws + (1 << 20);
    int* list            = (int*)(base);                           // 1024 ints
    float* bias_p        = (float*)(base + 4096);                  // 1024 f32
    unsigned char* g_prm = (unsigned char*)(base + 8192);          // 1024 bytes
    int* srt_cls         = (int*)(base + 12288);                   // 1000 ints
    int* srt_off         = (int*)(base + 16384);                   // 1000 ints
    int* srt_len         = (int*)(base + 20480);                   // 1000 ints

    build_csr_kernel<<<1, 1024, 0, stream>>>(labels, bias, list, bias_p, g_prm,
                                             srt_cls, srt_off, srt_len);
    convert_w_kernel<<<(N_COLS * F_SZ / 4) / 256, 256, 0, stream>>>(W, list, Wb);
    mhc_main_kernel<<<B_SZ / M_TILE, 1024, 0, stream>>>(feat, gp, Wb, bias_p, g_prm,
                                                        srt_cls, srt_off, srt_len, out);
}

// Round 7
// 254.507 us; speedup vs baseline: 1.5916x; 1.0941x over previous
//
#include <hip/hip_runtime.h>
#include <stdint.h>

#define B_SZ   32768
#define F_SZ   512
#define G_SZ   16
#define L_SZ   64
#define N_COLS 1024   // G*L
#define C_SZ   1000
#define M_TILE 64
#define A_STRIDE 520    // ushorts per LDS A row (512+8; keeps 16B alignment, breaks pow2 stride)
#define WT_STRIDE 20    // floats per transposed weighted col (16 rows + 4 pad).
                        // 20 = odd-multiple-of-4 word stride: b128 quartet = (5*col+quad)%8,
                        // 5 odd -> structured writes hit all 8 quartets evenly (structural-min
                        // 8 rounds/instr) and random gather cols spread uniformly.
#define SMEM_BYTES 81920  // max(A 64*520*2 = 66560, WT 1024*20*4 = 81920)

typedef __attribute__((ext_vector_type(8))) short short8;
typedef __attribute__((ext_vector_type(4))) float floatx4;

__device__ __forceinline__ unsigned short f2bf(float f) {
    unsigned int x = __float_as_uint(f);
    x += 0x7fffu + ((x >> 16) & 1u);   // RNE to bf16
    return (unsigned short)(x >> 16);
}

// Raw workgroup barrier WITHOUT the vmcnt(0) drain __syncthreads() implies.
// All sync points in mhc_main are LDS-only hazards -> lgkmcnt(0) suffices.
// Out-stores are never read back; global loads are reg-guarded by the compiler.
// Measured r3: this alone was 133 -> 120 us vs __syncthreads.
__device__ __forceinline__ void barrier_lgkm() {
    __builtin_amdgcn_sched_barrier(0);
    asm volatile("s_waitcnt lgkmcnt(0)" ::: "memory");
    __builtin_amdgcn_s_barrier();
    __builtin_amdgcn_sched_barrier(0);
}

// ---- kernel 1: invert label_ids into CSR with a parallel scan; emit the column
//      permutation (list), permuted bias, and per-slot group id ----
__global__ __launch_bounds__(1024) void build_csr_kernel(const int* __restrict__ label_ids,
                                                         const float* __restrict__ bias,
                                                         int* __restrict__ off,
                                                         int* __restrict__ list,
                                                         float* __restrict__ bias_p,
                                                         unsigned char* __restrict__ g_perm) {
    __shared__ int cnt[1024];   // counts -> inclusive scan (classes padded to 1024)
    __shared__ int cur[1024];   // scatter cursors
    const int t = threadIdx.x;            // 0..1023 == column index g*64+l
    cnt[t] = 0;
    __syncthreads();
    const int lbl = label_ids[t];
    atomicAdd(&cnt[lbl], 1);
    __syncthreads();
    // Hillis-Steele inclusive scan over 1024 entries
    int v = cnt[t];
    #pragma unroll
    for (int d = 1; d < 1024; d <<= 1) {
        int u = (t >= d) ? cnt[t - d] : 0;
        __syncthreads();
        v += u;
        cnt[t] = v;
        __syncthreads();
    }
    // exclusive offset for this thread's class slot
    int ex = (t == 0) ? 0 : cnt[t - 1];
    cur[t] = ex;
    if (t <= C_SZ) off[t] = (t == 0) ? 0 : cnt[t - 1];   // off[1000] == 1024
    __syncthreads();
    int pos = atomicAdd(&cur[lbl], 1);
    list[pos]   = t;
    bias_p[pos] = bias[t];
    g_perm[pos] = (unsigned char)(t >> 6);
}

// ---- kernel 2: W f32 -> bf16, rows permuted into CSR-list order ----
__global__ __launch_bounds__(256) void convert_w_kernel(const float* __restrict__ W,
                                                        const int* __restrict__ list,
                                                        unsigned short* __restrict__ Wb) {
    int idx = blockIdx.x * 256 + threadIdx.x;        // float4 index, 131072 total
    int row = idx >> 7;                              // output row j
    int c4  = idx & 127;
    int src = list[row];                             // original column
    const float4* W4 = (const float4*)W;
    float4 v = W4[src * 128 + c4];
    ushort4 u = make_ushort4(f2bf(v.x), f2bf(v.y), f2bf(v.z), f2bf(v.w));
    ((ushort4*)Wb)[idx] = u;
}

// ---- kernel 3: fused GEMM (bf16 MFMA) + weighting + contiguous-run gather ----
// Block: 1024 threads = 16 waves. Tile: 64 rows x ALL 1024 (permuted) cols. K=512.
// EXACT r3 structure (measured 120 us) except the weighted tile is TRANSPOSED:
// WT[col][16 rows], stride 20 words. One gather iteration = 4x ds_read_b128
// (was 16x ds_read_b32); write side = 4x ds_write_b128 (was 16x ds_write_b32).
// Stores stay r3-coalesced (thread t <-> class t) — r5 measured +30 MB L2
// partial-line write amplification (+20 us) from scattered stores; avoided here.
__global__ __launch_bounds__(1024, 4) void mhc_main_kernel(
        const float* __restrict__ feat,            // [B][512] f32
        const float* __restrict__ gp,              // [B][16]  f32
        const unsigned short* __restrict__ Wb,     // [1024][512] bf16, permuted rows
        const float* __restrict__ bias_p,          // [1024] f32, permuted
        const int* __restrict__ off,               // [1001]
        const unsigned char* __restrict__ g_perm,  // [1024] group of each permuted col
        float* __restrict__ out)                   // [B][1000] f32
{
    __shared__ __align__(16) char smem[SMEM_BYTES]; // A-stage aliased with WT tile
    __shared__ float gp_s[M_TILE * G_SZ];           // 64 rows x 16 groups
    __shared__ float bias_s[N_COLS];
    __shared__ unsigned char g_s[N_COLS];

    unsigned short* As = (unsigned short*)smem;
    float* WT = (float*)smem;

    const int t    = threadIdx.x;
    const int wave = t >> 6;          // 0..15
    const int lane = t & 63;
    const int m16  = lane & 15;
    const int quad = lane >> 4;       // 0..3
    const int r0   = blockIdx.x * M_TILE;

    // stage group_probs tile + permuted bias + per-col group
    gp_s[t]   = gp[r0 * G_SZ + t];
    bias_s[t] = bias_p[t];
    g_s[t]    = g_perm[t];

    // this thread's contiguous gather run (pass-invariant, lives in registers)
    int e0 = 0, e1 = 0;
    if (t < C_SZ) { e0 = off[t]; e1 = off[t + 1]; }

    // stage A: 64 rows x 512 f32 -> bf16 LDS, coalesced float4 reads
    {
        const float4* f4 = (const float4*)(feat + (size_t)r0 * F_SZ);
        #pragma unroll
        for (int i = 0; i < 8; ++i) {
            int idx = t + i * 1024;            // row = idx/128, c4 = idx%128
            int row = idx >> 7;
            int c4  = idx & 127;
            float4 v = f4[idx];
            ushort4 u = make_ushort4(f2bf(v.x), f2bf(v.y), f2bf(v.z), f2bf(v.w));
            *(ushort4*)(As + row * A_STRIDE + c4 * 4) = u;
        }
    }
    barrier_lgkm();   // A + gp/bias/g_s visible

    const floatx4 zero = {0.f, 0.f, 0.f, 0.f};
    floatx4 acc[4][4];
    #pragma unroll
    for (int i = 0; i < 4; ++i)
        #pragma unroll
        for (int j = 0; j < 4; ++j) acc[i][j] = zero;

    const unsigned short* aBase = As + m16 * A_STRIDE + quad * 8;
    const unsigned short* bBase = Wb + (size_t)(wave * 64 + m16) * F_SZ + quad * 8;

    #pragma unroll 4
    for (int kt = 0; kt < 16; ++kt) {             // K step = 32
        short8 a[4];
        #pragma unroll
        for (int rt = 0; rt < 4; ++rt)
            a[rt] = *(const short8*)(aBase + rt * 16 * A_STRIDE + kt * 32);
        #pragma unroll
        for (int ct = 0; ct < 4; ++ct) {
            short8 b = *(const short8*)(bBase + ct * 16 * F_SZ + kt * 32);
            #pragma unroll
            for (int rt = 0; rt < 4; ++rt)
                acc[rt][ct] = __builtin_amdgcn_mfma_f32_16x16x32_bf16(a[rt], b, acc[rt][ct], 0, 0, 0);
        }
    }

    // epilogue: 4 passes of 16 rows. Transposed weighted tile -> b128 gather,
    // coalesced b32 stores (thread t == class t).
    #pragma unroll
    for (int p = 0; p < 4; ++p) {
        barrier_lgkm();   // pass 0: K-loop A-LDS reads done; later: prior gather reads done
        #pragma unroll
        for (int ct = 0; ct < 4; ++ct) {
            int col = wave * 64 + ct * 16 + m16;
            int g   = g_s[col];
            float bi = bias_s[col];
            floatx4 w;
            #pragma unroll
            for (int r = 0; r < 4; ++r) {
                int rl = quad * 4 + r;                       // local row 0..15 (C/D layout)
                w[r] = gp_s[(p * 16 + rl) * G_SZ + g] * (acc[p][ct][r] + bi);
            }
            *(floatx4*)(WT + col * WT_STRIDE + quad * 4) = w;  // ds_write_b128
        }
        barrier_lgkm();   // WT visible to gatherers
        if (t < C_SZ) {
            floatx4 s0 = zero, s1 = zero, s2 = zero, s3 = zero;
            for (int j = e0; j < e1; ++j) {
                const float* cb = WT + j * WT_STRIDE;
                s0 += *(const floatx4*)(cb + 0);
                s1 += *(const floatx4*)(cb + 4);
                s2 += *(const floatx4*)(cb + 8);
                s3 += *(const floatx4*)(cb + 12);
            }
            size_t rb = (size_t)(r0 + p * 16) * C_SZ + t;    // coalesced column t
            #pragma unroll
            for (int r = 0; r < 4; ++r) {
                out[rb + (size_t)(r +  0) * C_SZ] = s0[r];
                out[rb + (size_t)(r +  4) * C_SZ] = s1[r];
                out[rb + (size_t)(r +  8) * C_SZ] = s2[r];
                out[rb + (size_t)(r + 12) * C_SZ] = s3[r];
            }
        }
    }
}

extern "C" void kernel_launch(void* const* d_in, const int* in_sizes, int n_in,
                              void* d_out, int out_size, void* d_ws, size_t ws_size,
                              hipStream_t stream) {
    const float* feat  = (const float*)d_in[0];
    const float* gp    = (const float*)d_in[1];
    const float* W     = (const float*)d_in[2];
    const float* bias  = (const float*)d_in[3];
    const int* labels  = (const int*)d_in[4];
    float* out = (float*)d_out;

    unsigned short* Wb = (unsigned short*)d_ws;                    // 1 MiB bf16 W (permuted)
    char* base = (char*)d_ws + (1 << 20);
    int* off             = (int*)base;                             // 1001 ints (pad 4 KB)
    int* list            = (int*)(base + 4096);                    // 1024 ints
    float* bias_p        = (float*)(base + 8192);                  // 1024 f32
    unsigned char* g_prm = (unsigned char*)(base + 12288);         // 1024 bytes

    build_csr_kernel<<<1, 1024, 0, stream>>>(labels, bias, off, list, bias_p, g_prm);
    convert_w_kernel<<<(N_COLS * F_SZ / 4) / 256, 256, 0, stream>>>(W, list, Wb);
    mhc_main_kernel<<<B_SZ / M_TILE, 1024, 0, stream>>>(feat, gp, Wb, bias_p, off, g_prm, out);
}